// Round 7
// baseline (92.514 us; speedup 1.0000x reference)
//
#include <hip/hip_runtime.h>

typedef float f32x2 __attribute__((ext_vector_type(2)));
typedef float f32x4 __attribute__((ext_vector_type(4)));
typedef short bf16x8 __attribute__((ext_vector_type(8)));

// LDS map (bytes), 128-thread blocks (2 waves):
//   [0, 50240)        per-wave raw-x DMA buffers: 2 waves x 2 bufs x 12560
//                     (12544 fp32 data + 16B zero pad; setup stages W1/W2 in [0,7232))
//   [50240, 57408)    W12 bf16 [f2:16][k:224] stride 448B (preloaded to regs, then
//                     ALIASED by per-wave y: 2 x 16 rows x 144B = 4608B)
//   [57408, 57472)    b12 (16 f32)
// Total 57472 B -> 2 blocks/CU (114.9 KB of 160), 4 waves/CU. Latency hiding
// comes from DMA depth (13-26 KB outstanding per wave), not occupancy.
#define XBUF 12560
#define XW_STRIDE (2 * XBUF)
#define XTOT (2 * XW_STRIDE)      // 50240
#define W12OFF XTOT
#define YOFF XTOT                 // y aliases W12 after fragment preload
#define YS 144
#define BOFF (XTOT + 7168)        // 57408
#define SMEM_BYTES (BOFF + 64)

// RNE float->bf16 on plain integer types.
__device__ __forceinline__ unsigned short f2bf(float f) {
  unsigned u = __builtin_bit_cast(unsigned, f);
  u += 0x7FFFu + ((u >> 16) & 1u);
  return (unsigned short)(u >> 16);
}
__device__ __forceinline__ unsigned packbf2(float a, float b) {
  return (unsigned)f2bf(a) | ((unsigned)f2bf(b) << 16);
}

// Async global->LDS DMA, 16B per lane. LDS dest = wave-uniform base + lane*16
// (HW adds the lane offset); global src is per-lane.
__device__ __forceinline__ void dma16(const void* g, void* l) {
  __builtin_amdgcn_global_load_lds(
      (const __attribute__((address_space(1))) unsigned*)g,
      (__attribute__((address_space(3))) unsigned*)l, 16, 0, 0);
}

__global__ __launch_bounds__(128) void mnist_mfma(
    const float* __restrict__ x, const float* __restrict__ W1,
    const float* __restrict__ b1, const float* __restrict__ W2,
    const float* __restrict__ b2, const float* __restrict__ W3,
    const float* __restrict__ b3, float* __restrict__ out, int nimg)
{
  __shared__ __align__(16) char smem[SMEM_BYTES];
  float* smemF = (float*)smem;
  const int tid = threadIdx.x;
  const int lane = tid & 63;
  const int wavelocal = tid >> 6;   // 0..1

  // Zero the 16B pad of each DMA buffer (read by the last image's J=1 edge rows).
  if (tid < 16) {
    int w = tid >> 3, b = (tid >> 2) & 1, d = tid & 3;
    *(unsigned*)(smem + w * XW_STRIDE + b * XBUF + 12544 + d * 4) = 0;
  }
  // ---- setup: stage W1/W2, compose W12 (k = rr*16 + cc, cc 14..15 = 0) ----
  for (int i = tid; i < 784; i += 128)  smemF[i] = W1[i];
  for (int i = tid; i < 1024; i += 128) smemF[784 + i] = W2[i];
  __syncthreads();

  unsigned short* w12b = (unsigned short*)(smem + W12OFF);
  for (int e = tid; e < 3584; e += 128) {
    int f2 = e / 224, k = e - f2 * 224;
    int rr = k >> 4, cc = k & 15;
    float s = 0.f;
    if (cc < 14) {
      int pp = (rr % 7) * 7 + (cc % 7);          // within-patch pixel
      int q  = (rr / 7) * 2 + (cc / 7);          // patch position in quadrant
#pragma unroll
      for (int f = 0; f < 16; ++f)
        s = fmaf(smemF[f * 49 + pp], smemF[784 + f2 * 64 + q * 16 + f], s);
    }
    w12b[f2 * 224 + k] = f2bf(s);
  }
  if (tid < 16) {                                // b12 = b2 + b1-through-W2
    float s = b2[tid];
#pragma unroll
    for (int k = 0; k < 64; ++k)
      s = fmaf(b1[k & 15], smemF[784 + tid * 64 + k], s);
    smemF[BOFF / 4 + tid] = s;
  }
  __syncthreads();

  // ---- preload fragments into registers ----------------------------------
  bf16x8 wfrag[7];                               // W12 B-frags (28 VGPRs)
#pragma unroll
  for (int i = 0; i < 7; ++i)
    wfrag[i] = *(const bf16x8*)(smem + W12OFF + (lane & 15) * 448 + (lane >> 4) * 16 + i * 64);

  bf16x8 w3f[2];                                 // W3 A-frags (rows>=10 zero)
  {
    int o = lane & 15, kb = (lane >> 4) * 8;
#pragma unroll
    for (int mi = 0; mi < 2; ++mi) {
      float v[8];
#pragma unroll
      for (int j = 0; j < 8; ++j)
        v[j] = (o < 10) ? W3[o * 64 + kb + 32 * mi + j] : 0.f;
      unsigned t[4];
      t[0] = packbf2(v[0], v[1]); t[1] = packbf2(v[2], v[3]);
      t[2] = packbf2(v[4], v[5]); t[3] = packbf2(v[6], v[7]);
      w3f[mi] = __builtin_bit_cast(bf16x8, *(unsigned(*)[4])t);
    }
  }
  const float b12v = smemF[BOFF / 4 + (lane & 15)];
  float b3v[4];
#pragma unroll
  for (int r = 0; r < 4; ++r) {
    int o = (lane >> 4) * 4 + r;
    b3v[r] = (o < 10) ? b3[o] : 0.f;
  }
  __syncthreads();   // W12 fully consumed by all waves; y may alias it now.

  // ---- per-lane A-fragment base in the raw raster tile -------------------
  // Row = im*4 + I*2 + J (lane&15); k-block m0 = lane>>4: rr0 = m0>>1, half = m0&1.
  // k' = rr*16+cc  ->  pixel (I*14+rr, J*14+cc): 8 consecutive floats, 8B-aligned.
  int abase;
  {
    int row = lane & 15, m0 = lane >> 4;
    int im = row >> 2, q = row & 3, I = q >> 1, J = q & 1;
    abase = im * 3136 + (I * 14 + (m0 >> 1)) * 112 + J * 56 + (m0 & 1) * 32;
  }
  const int XW = wavelocal * XW_STRIDE;
  const unsigned ywb = YOFF + wavelocal * 2304 + (lane & 15) * 2;
  const unsigned yrd = YOFF + wavelocal * 2304 + (lane & 15) * YS + (lane >> 4) * 16;

  const int NU = nimg >> 4;                      // 16-image units
  const int WST = (int)(gridDim.x << 1);         // total waves
  const int w0 = (int)(blockIdx.x << 1) + wavelocal;
  const int nu = (w0 < NU) ? ((NU - w0 + WST - 1) / WST) : 0;
  const int send = nu * 4;                       // flattened sub-batch count

  auto issue = [&](int s) {                      // DMA one 4-image block (12.25 KB)
    int unit = w0 + (s >> 2) * WST;
    const char* gp = (const char*)x + (size_t)(unit * 4 + (s & 3)) * 12544 + (size_t)(lane * 16);
    char* lp = smem + XW + (s & 1) * XBUF;
#pragma unroll
    for (int it = 0; it < 12; ++it) dma16(gp + it * 1024, lp + it * 1024);
    if (lane < 16) dma16(gp + 12288, lp + 12288);
  };

  if (send > 0) issue(0);
  if (send > 1) issue(1);

  for (int s = 0; s < send; ++s) {
    // Counted wait: 13 newer DMAs (next buffer) stay in flight across the wait.
    if (s + 1 < send) { asm volatile("s_waitcnt vmcnt(13)" ::: "memory"); }
    else              { asm volatile("s_waitcnt vmcnt(0)"  ::: "memory"); }
    __builtin_amdgcn_sched_barrier(0);

    const f32x2* ap = (const f32x2*)(smem + XW + (s & 1) * XBUF + abase);
    f32x4 acc = {0.f, 0.f, 0.f, 0.f};
#pragma unroll
    for (int i = 0; i < 7; ++i) {                // GEMM1: K=224 in 7 MFMAs
      f32x2 a0 = ap[i * 28], a1 = ap[i * 28 + 1], a2 = ap[i * 28 + 2], a3 = ap[i * 28 + 3];
      unsigned u[4] = { packbf2(a0.x, a0.y), packbf2(a1.x, a1.y),
                        packbf2(a2.x, a2.y), packbf2(a3.x, a3.y) };
      bf16x8 afr = __builtin_bit_cast(bf16x8, *(unsigned(*)[4])u);
      acc = __builtin_amdgcn_mfma_f32_16x16x32_bf16(afr, wfrag[i], acc, 0, 0, 0);
    }
    if (s + 2 < send) issue(s + 2);              // refill this buffer 2-deep

    // bias + ReLU + bf16 -> y (row = img, k = q*16+f2)
    unsigned yb = ywb + (unsigned)((s & 3) * 4 + (lane >> 4)) * YS;
#pragma unroll
    for (int r = 0; r < 4; ++r) {
      float yv = fmaxf(acc[r] + b12v, 0.f);
      *(unsigned short*)(smem + yb + r * 32) = f2bf(yv);
    }

    if ((s & 3) == 3) {                          // unit epilogue
      f32x4 z4 = {0.f, 0.f, 0.f, 0.f};
#pragma unroll
      for (int mi = 0; mi < 2; ++mi) {
        bf16x8 bfr = *(const bf16x8*)(smem + yrd + 64 * mi);
        z4 = __builtin_amdgcn_mfma_f32_16x16x32_bf16(w3f[mi], bfr, z4, 0, 0, 0);
      }
      float zv[4], mval = -3.0e38f;
#pragma unroll
      for (int r = 0; r < 4; ++r) {
        zv[r] = z4[r] + b3v[r];
        bool valid = ((lane >> 4) * 4 + r) < 10;
        mval = fmaxf(mval, valid ? zv[r] : -3.0e38f);
      }
      mval = fmaxf(mval, __shfl_xor(mval, 16, 64));
      mval = fmaxf(mval, __shfl_xor(mval, 32, 64));
      float ssum = 0.f;
#pragma unroll
      for (int r = 0; r < 4; ++r) {
        bool valid = ((lane >> 4) * 4 + r) < 10;
        ssum += valid ? __expf(zv[r] - mval) : 0.f;
      }
      ssum += __shfl_xor(ssum, 16, 64);
      ssum += __shfl_xor(ssum, 32, 64);
      const float lse = mval + __logf(ssum);
      int unit = w0 + (s >> 2) * WST;
      float* op = out + (size_t)(unit * 16 + (lane & 15)) * 10;
#pragma unroll
      for (int r = 0; r < 4; ++r) {
        int o = (lane >> 4) * 4 + r;
        if (o < 10) op[o] = zv[r] - lse;
      }
    }
  }
}

extern "C" void kernel_launch(void* const* d_in, const int* in_sizes, int n_in,
                              void* d_out, int out_size, void* d_ws, size_t ws_size,
                              hipStream_t stream) {
  const float* x  = (const float*)d_in[0];
  const float* W1 = (const float*)d_in[1];
  const float* b1 = (const float*)d_in[2];
  const float* W2 = (const float*)d_in[3];
  const float* b2 = (const float*)d_in[4];
  const float* W3 = (const float*)d_in[5];
  const float* b3 = (const float*)d_in[6];
  float* out = (float*)d_out;

  const int nimg = in_sizes[0] / 784;  // 131072
  // 512 blocks x 128 threads = 1024 waves -> exactly 8 units/wave.
  // 2 blocks/CU (57.4 KB LDS); saturation via 2-deep DMA, not occupancy.
  mnist_mfma<<<512, 128, 0, stream>>>(x, W1, b1, W2, b2, W3, b3, out, nimg);
}

// Round 8
// 88.621 us; speedup vs baseline: 1.0439x; 1.0439x over previous
//
#include <hip/hip_runtime.h>

typedef float f32x4 __attribute__((ext_vector_type(4)));
typedef short bf16x8 __attribute__((ext_vector_type(8)));

// Main-kernel LDS (bytes): x-stage 4 waves x 16 rows x 464B = 29696,
// y 4 waves x 16 rows x 144B = 9216.  Total 38912 -> 4 blocks/CU.
#define XS 464
#define YOFF 29696
#define YS 144
#define SMEMB 38912

// Workspace layout (bytes) — all weight data pre-composed in FRAGMENT order:
//   [0,7168)      W12 B-frags:  frag i (0..6) x lane x 16B  (k=i*32+(lane>>4)*8+j, f2=lane&15)
//   [7168,9216)   W3  A-frags:  mi (0..1) x lane x 16B
//   [9216,10240)  b3 frags:     lane x 4 f32  (o=(lane>>4)*4+r, 0 for o>=10)
//   [10240,10496) b12:          lane x f32    (b12[lane&15])
#define WS_WF   0
#define WS_W3F  7168
#define WS_B3F  9216
#define WS_B12  10240
#define WS_NEED 10496

// RNE float->bf16 on plain integer types.
__device__ __forceinline__ unsigned short f2bf(float f) {
  unsigned u = __builtin_bit_cast(unsigned, f);
  u += 0x7FFFu + ((u >> 16) & 1u);
  return (unsigned short)(u >> 16);
}
__device__ __forceinline__ unsigned packbf2(float a, float b) {
  return (unsigned)f2bf(a) | ((unsigned)f2bf(b) << 16);
}

// ---------------- kernel A: compose weights once into d_ws ----------------
__global__ void compose_k(const float* __restrict__ W1, const float* __restrict__ b1,
                          const float* __restrict__ W2, const float* __restrict__ b2,
                          const float* __restrict__ W3, const float* __restrict__ b3,
                          char* __restrict__ ws)
{
  __shared__ float sm[1808];                     // W1 (784) + W2 (1024)
  const int tid = threadIdx.x;
  for (int i = tid; i < 784; i += 256)  sm[i] = W1[i];
  for (int i = tid; i < 1024; i += 256) sm[784 + i] = W2[i];
  __syncthreads();

  // W12[k= rr*14+cc (196, pad to 224)][f2] = sum_f W1[f][pp] * W2[f2][q*16+f],
  // written directly in B-fragment element order e = i*512 + lane*8 + j.
  unsigned short* wf = (unsigned short*)(ws + WS_WF);
  for (int e = tid; e < 3584; e += 256) {
    int i = e >> 9, rem = e & 511, lane = rem >> 3, j = rem & 7;
    int f2 = lane & 15, kb = lane >> 4;
    int k = i * 32 + kb * 8 + j;
    float s = 0.f;
    if (k < 196) {
      int rr = k / 14, cc = k - rr * 14;
      int pp = (rr % 7) * 7 + (cc % 7);          // within-patch pixel
      int q  = (rr / 7) * 2 + (cc / 7);          // patch position in quadrant
#pragma unroll
      for (int f = 0; f < 16; ++f)
        s = fmaf(sm[f * 49 + pp], sm[784 + f2 * 64 + q * 16 + f], s);
    }
    wf[e] = f2bf(s);
  }
  if (tid < 128) {                               // W3 A-frags (rows>=10 zero)
    int mi = tid >> 6, lane = tid & 63;
    int o = lane & 15, kb = (lane >> 4) * 8;
    float v[8];
#pragma unroll
    for (int j = 0; j < 8; ++j)
      v[j] = (o < 10) ? W3[o * 64 + kb + 32 * mi + j] : 0.f;
    unsigned t[4];
    t[0] = packbf2(v[0], v[1]); t[1] = packbf2(v[2], v[3]);
    t[2] = packbf2(v[4], v[5]); t[3] = packbf2(v[6], v[7]);
    *(f32x4*)(ws + WS_W3F + mi * 1024 + lane * 16) = __builtin_bit_cast(f32x4, *(unsigned(*)[4])t);
  }
  if (tid < 64) {                                // b3 frags
    float v[4];
#pragma unroll
    for (int r = 0; r < 4; ++r) {
      int o = (tid >> 4) * 4 + r;
      v[r] = (o < 10) ? b3[o] : 0.f;
    }
    *(f32x4*)(ws + WS_B3F + tid * 16) = *(f32x4*)v;
  }
  if (tid < 64) {                                // b12 = b2 + b1-through-W2
    int f2 = tid & 15;
    float s = b2[f2];
#pragma unroll
    for (int k = 0; k < 64; ++k)
      s = fmaf(b1[k & 15], sm[784 + f2 * 64 + k], s);
    *(float*)(ws + WS_B12 + tid * 4) = s;
  }
}

// ---------------- kernel B: barrier-free streaming main kernel ------------
__global__ __launch_bounds__(256, 2) void mnist_main(
    const float* __restrict__ x, const char* __restrict__ ws,
    float* __restrict__ out, int nimg)
{
  __shared__ __align__(16) char smem[SMEMB];
  const int tid = threadIdx.x;
  const int lane = tid & 63;
  const int waveid = tid >> 6;

  // fragment loads straight from ws (10 coalesced dwordx4 + 1 dword)
  bf16x8 wfrag[7];
#pragma unroll
  for (int i = 0; i < 7; ++i)
    wfrag[i] = *(const bf16x8*)(ws + WS_WF + i * 1024 + lane * 16);
  bf16x8 w3f[2];
#pragma unroll
  for (int mi = 0; mi < 2; ++mi)
    w3f[mi] = *(const bf16x8*)(ws + WS_W3F + mi * 1024 + lane * 16);
  const f32x4 b3v = *(const f32x4*)(ws + WS_B3F + lane * 16);
  const float b12v = *(const float*)(ws + WS_B12 + lane * 4);

  // per-wave zero of x-stage K-pad (bytes [392,464) of each row)
  char* xw = smem + waveid * 7424;
#pragma unroll
  for (int j = 0; j < 5; ++j) {
    int idx = lane + 64 * j;
    if (idx < 288) {
      int row = idx / 18, d = idx - row * 18;
      *(unsigned*)(xw + row * XS + 392 + d * 4) = 0;
    }
  }

  // staging addresses: raster float4 -> quadrant-stream bf16 pairs
  unsigned wa0[13]; unsigned strm = 0;
#pragma unroll
  for (int it = 0; it < 13; ++it) {
    int gi = lane + 64 * it;
    int im = gi / 196, rem = gi - im * 196;      // image, float4 within image
    int rr = rem / 7, t = rem - rr * 7;          // pixel row, 4-px group
    int c2 = 2 * t;                              // first bf16-pair column
    int J = c2 / 7, cq = c2 - 7 * J;
    int row = im * 4 + (rr / 14) * 2 + J;        // M-row = im*4 + (I*2+J)
    int kp = (rr % 14) * 7 + cq;                 // pair index in quadrant
    wa0[it] = waveid * 7424 + row * XS + kp * 4;
    if (t == 3) strm |= (1u << it);              // second pair crosses J-half
  }

  const unsigned xrd = waveid * 7424 + (lane & 15) * XS + (lane >> 4) * 16;
  const unsigned ywb = YOFF + waveid * 2304 + (lane & 15) * 2;
  const unsigned yrd = YOFF + waveid * 2304 + (lane & 15) * YS + (lane >> 4) * 16;

  const int NU = nimg >> 4;                      // 16-image units
  const int WST = (int)(gridDim.x << 2);         // total waves
  const int w0 = (int)(blockIdx.x << 2) + waveid;
  const int ng4 = nimg >> 2;                     // 4-image groups

  f32x4 cur[13];
  const f32x4* __restrict__ xq0 = (const f32x4*)x;
  auto issue4 = [&](int g4) {                    // 13 coalesced dwordx4 loads
    const f32x4* p = xq0 + (size_t)g4 * 784;
#pragma unroll
    for (int it = 0; it < 12; ++it) cur[it] = p[lane + 64 * it];
    if (lane < 16) cur[12] = p[768 + lane];
  };

  if (w0 < NU) issue4(w0 * 4);

  for (int u = w0; u < NU; u += WST) {
#pragma unroll 1
    for (int sb = 0; sb < 4; ++sb) {
      // stage cur -> LDS (compiler inserts the vmcnt wait on cur)
#pragma unroll
      for (int it = 0; it < 13; ++it) {
        if (it == 12 && lane >= 16) continue;
        f32x4 v = cur[it];
        unsigned a0 = wa0[it];
        unsigned d = ((strm >> it) & 1) ? 440u : 4u;
        *(unsigned*)(smem + a0) = packbf2(v.x, v.y);
        *(unsigned*)(smem + a0 + d) = packbf2(v.z, v.w);
      }
      // prefetch next 4-image group (1 sub-batch deep)
      int ng = (sb < 3) ? (u * 4 + sb + 1) : ((u + WST) * 4);
      if (ng < ng4) issue4(ng);
      // GEMM1: y(16 rows x 16 f2) = P(16 x 224) * W12(224 x 16)
      f32x4 acc = {0.f, 0.f, 0.f, 0.f};
#pragma unroll
      for (int i = 0; i < 7; ++i) {
        bf16x8 a = *(const bf16x8*)(smem + xrd + 64 * i);
        acc = __builtin_amdgcn_mfma_f32_16x16x32_bf16(a, wfrag[i], acc, 0, 0, 0);
      }
      // bias + ReLU + bf16 -> y LDS (same-wave region; lgkmcnt orders RAW)
      unsigned yb = ywb + (unsigned)(sb * 4 + (lane >> 4)) * YS;
#pragma unroll
      for (int r = 0; r < 4; ++r) {
        float yv = fmaxf(acc[r] + b12v, 0.f);
        *(unsigned short*)(smem + yb + r * 32) = f2bf(yv);
      }
    }
    // GEMM2: z^T(16 o x 16 img) = W3(16x64) * y^T(64x16) over the unit
    f32x4 z4 = {0.f, 0.f, 0.f, 0.f};
#pragma unroll
    for (int mi = 0; mi < 2; ++mi) {
      bf16x8 bfr = *(const bf16x8*)(smem + yrd + 64 * mi);
      z4 = __builtin_amdgcn_mfma_f32_16x16x32_bf16(w3f[mi], bfr, z4, 0, 0, 0);
    }
    // log_softmax over o = (lane>>4)*4 + r (10 valid), img = lane&15
    float zv[4], mval = -3.0e38f;
#pragma unroll
    for (int r = 0; r < 4; ++r) {
      zv[r] = z4[r] + b3v[r];
      bool valid = ((lane >> 4) * 4 + r) < 10;
      mval = fmaxf(mval, valid ? zv[r] : -3.0e38f);
    }
    mval = fmaxf(mval, __shfl_xor(mval, 16, 64));
    mval = fmaxf(mval, __shfl_xor(mval, 32, 64));
    float ssum = 0.f;
#pragma unroll
    for (int r = 0; r < 4; ++r) {
      bool valid = ((lane >> 4) * 4 + r) < 10;
      ssum += valid ? __expf(zv[r] - mval) : 0.f;
    }
    ssum += __shfl_xor(ssum, 16, 64);
    ssum += __shfl_xor(ssum, 32, 64);
    const float lse = mval + __logf(ssum);
    float* op = out + (size_t)(u * 16 + (lane & 15)) * 10;
#pragma unroll
    for (int r = 0; r < 4; ++r) {
      int o = (lane >> 4) * 4 + r;
      if (o < 10) op[o] = zv[r] - lse;
    }
  }
}

// ---------------- fallback (r6 self-contained kernel) if ws too small -----
__global__ __launch_bounds__(256, 2) void mnist_fb(
    const float* __restrict__ x, const float* __restrict__ W1,
    const float* __restrict__ b1, const float* __restrict__ W2,
    const float* __restrict__ b2, const float* __restrict__ W3,
    const float* __restrict__ b3, float* __restrict__ out, int nimg)
{
  __shared__ __align__(16) char smem[38976];
  float* smemF = (float*)smem;
  const int tid = threadIdx.x;
  const int lane = tid & 63;
  const int waveid = tid >> 6;
  for (int i = tid; i < 784; i += 256) smemF[i] = W1[i];
  for (int i = tid; i < 1024; i += 256) smemF[784 + i] = W2[i];
  __syncthreads();
  unsigned short* w12b = (unsigned short*)(smem + 29696);
  for (int e = tid; e < 3136; e += 256) {
    int f2 = e / 196, k = e - f2 * 196;
    int r14 = k / 14, c14 = k - r14 * 14;
    int pp = (r14 % 7) * 7 + (c14 % 7);
    int q = (r14 / 7) * 2 + (c14 / 7);
    float s = 0.f;
#pragma unroll
    for (int f = 0; f < 16; ++f)
      s = fmaf(smemF[f * 49 + pp], smemF[784 + f2 * 64 + q * 16 + f], s);
    w12b[f2 * 232 + k] = f2bf(s);
  }
  for (int e = tid; e < 576; e += 256) {
    int f2 = e / 36;
    w12b[f2 * 232 + 196 + (e - f2 * 36)] = 0;
  }
  if (tid < 16) {
    float s = b2[tid];
#pragma unroll
    for (int k = 0; k < 64; ++k) s = fmaf(b1[k & 15], smemF[784 + tid * 64 + k], s);
    smemF[38912 / 4 + tid] = s;
  }
  __syncthreads();
  bf16x8 wfrag[7];
#pragma unroll
  for (int i = 0; i < 7; ++i)
    wfrag[i] = *(const bf16x8*)(smem + 29696 + (lane & 15) * 464 + (lane >> 4) * 16 + i * 64);
  bf16x8 w3f[2];
  {
    int o = lane & 15, kb = (lane >> 4) * 8;
#pragma unroll
    for (int mi = 0; mi < 2; ++mi) {
      float v[8];
#pragma unroll
      for (int j = 0; j < 8; ++j) v[j] = (o < 10) ? W3[o * 64 + kb + 32 * mi + j] : 0.f;
      unsigned t[4];
      t[0] = packbf2(v[0], v[1]); t[1] = packbf2(v[2], v[3]);
      t[2] = packbf2(v[4], v[5]); t[3] = packbf2(v[6], v[7]);
      w3f[mi] = __builtin_bit_cast(bf16x8, *(unsigned(*)[4])t);
    }
  }
  const float b12v = smemF[38912 / 4 + (lane & 15)];
  float b3v[4];
#pragma unroll
  for (int r = 0; r < 4; ++r) {
    int o = (lane >> 4) * 4 + r;
    b3v[r] = (o < 10) ? b3[o] : 0.f;
  }
  __syncthreads();
  char* xw = smem + waveid * 7424;
#pragma unroll
  for (int j = 0; j < 5; ++j) {
    int idx = lane + 64 * j;
    if (idx < 288) {
      int row = idx / 18, d = idx - row * 18;
      *(unsigned*)(xw + row * 464 + 392 + d * 4) = 0;
    }
  }
  unsigned wa0[13]; unsigned strm = 0;
#pragma unroll
  for (int it = 0; it < 13; ++it) {
    int gi = lane + 64 * it;
    int im = gi / 196, rem = gi - im * 196;
    int rr = rem / 7, t = rem - rr * 7;
    int c2 = 2 * t;
    int J = c2 / 7, cq = c2 - 7 * J;
    int row = im * 4 + (rr / 14) * 2 + J;
    int kp = (rr % 14) * 7 + cq;
    wa0[it] = waveid * 7424 + row * 464 + kp * 4;
    if (t == 3) strm |= (1u << it);
  }
  const unsigned xrd = waveid * 7424 + (lane & 15) * 464 + (lane >> 4) * 16;
  const unsigned ywb = 29696 + waveid * 2304 + (lane & 15) * 2;
  const unsigned yrd = 29696 + waveid * 2304 + (lane & 15) * 144 + (lane >> 4) * 16;
  const int NU = nimg >> 4;
  const int WST = (int)(gridDim.x << 2);
  const int w0 = (int)(blockIdx.x << 2) + waveid;
  const int ng4 = nimg >> 2;
  f32x4 cur[13];
  const f32x4* __restrict__ xq0 = (const f32x4*)x;
  auto issue4 = [&](int g4) {
    const f32x4* p = xq0 + (size_t)g4 * 784;
#pragma unroll
    for (int it = 0; it < 12; ++it) cur[it] = p[lane + 64 * it];
    if (lane < 16) cur[12] = p[768 + lane];
  };
  if (w0 < NU) issue4(w0 * 4);
  for (int u = w0; u < NU; u += WST) {
#pragma unroll 1
    for (int sb = 0; sb < 4; ++sb) {
#pragma unroll
      for (int it = 0; it < 13; ++it) {
        if (it == 12 && lane >= 16) continue;
        f32x4 v = cur[it];
        unsigned a0 = wa0[it];
        unsigned d = ((strm >> it) & 1) ? 440u : 4u;
        *(unsigned*)(smem + a0) = packbf2(v.x, v.y);
        *(unsigned*)(smem + a0 + d) = packbf2(v.z, v.w);
      }
      int ng = (sb < 3) ? (u * 4 + sb + 1) : ((u + WST) * 4);
      if (ng < ng4) issue4(ng);
      f32x4 acc = {0.f, 0.f, 0.f, 0.f};
#pragma unroll
      for (int i = 0; i < 7; ++i) {
        bf16x8 a = *(const bf16x8*)(smem + xrd + 64 * i);
        acc = __builtin_amdgcn_mfma_f32_16x16x32_bf16(a, wfrag[i], acc, 0, 0, 0);
      }
      unsigned yb = ywb + (unsigned)(sb * 4 + (lane >> 4)) * 144;
#pragma unroll
      for (int r = 0; r < 4; ++r) {
        float yv = fmaxf(acc[r] + b12v, 0.f);
        *(unsigned short*)(smem + yb + r * 32) = f2bf(yv);
      }
    }
    f32x4 z4 = {0.f, 0.f, 0.f, 0.f};
#pragma unroll
    for (int mi = 0; mi < 2; ++mi) {
      bf16x8 bfr = *(const bf16x8*)(smem + yrd + 64 * mi);
      z4 = __builtin_amdgcn_mfma_f32_16x16x32_bf16(w3f[mi], bfr, z4, 0, 0, 0);
    }
    float zv[4], mval = -3.0e38f;
#pragma unroll
    for (int r = 0; r < 4; ++r) {
      zv[r] = z4[r] + b3v[r];
      bool valid = ((lane >> 4) * 4 + r) < 10;
      mval = fmaxf(mval, valid ? zv[r] : -3.0e38f);
    }
    mval = fmaxf(mval, __shfl_xor(mval, 16, 64));
    mval = fmaxf(mval, __shfl_xor(mval, 32, 64));
    float ssum = 0.f;
#pragma unroll
    for (int r = 0; r < 4; ++r) {
      bool valid = ((lane >> 4) * 4 + r) < 10;
      ssum += valid ? __expf(zv[r] - mval) : 0.f;
    }
    ssum += __shfl_xor(ssum, 16, 64);
    ssum += __shfl_xor(ssum, 32, 64);
    const float lse = mval + __logf(ssum);
    float* op = out + (size_t)(u * 16 + (lane & 15)) * 10;
#pragma unroll
    for (int r = 0; r < 4; ++r) {
      int o = (lane >> 4) * 4 + r;
      if (o < 10) op[o] = zv[r] - lse;
    }
  }
}

extern "C" void kernel_launch(void* const* d_in, const int* in_sizes, int n_in,
                              void* d_out, int out_size, void* d_ws, size_t ws_size,
                              hipStream_t stream) {
  const float* x  = (const float*)d_in[0];
  const float* W1 = (const float*)d_in[1];
  const float* b1 = (const float*)d_in[2];
  const float* W2 = (const float*)d_in[3];
  const float* b2 = (const float*)d_in[4];
  const float* W3 = (const float*)d_in[5];
  const float* b3 = (const float*)d_in[6];
  float* out = (float*)d_out;

  const int nimg = in_sizes[0] / 784;  // 131072
  if (ws_size >= WS_NEED) {
    compose_k<<<1, 256, 0, stream>>>(W1, b1, W2, b2, W3, b3, (char*)d_ws);
    mnist_main<<<1024, 256, 0, stream>>>(x, (const char*)d_ws, out, nimg);
  } else {
    mnist_fb<<<1024, 256, 0, stream>>>(x, W1, b1, W2, b2, W3, b3, out, nimg);
  }
}

// Round 9
// 87.531 us; speedup vs baseline: 1.0569x; 1.0125x over previous
//
#include <hip/hip_runtime.h>

typedef float f32x4 __attribute__((ext_vector_type(4)));
typedef short bf16x8 __attribute__((ext_vector_type(8)));

// LDS map (bytes):
//   [0, 29696)      per-wave x-stage: 4 waves x 16 rows x 464B (224 bf16 + pad)
//                   (setup reuses [0,7232) to stage raw W1/W2 for compose)
//   [29696, 37120)  W12 bf16 (setup only; preloaded to regs, then DEAD)
//   [29696, 38912)  per-wave y (ALIASES W12 after preload): 4 x 16 x 144B
//   [38912, 38976)  b12 (16 f32)
// Total 38976 B -> 4 blocks/CU (155.9 KB of 160 KB).
#define XS 464
#define WOFF 29696
#define YOFF 29696
#define YS 144
#define BOFF 38912

// RNE float->bf16 on plain integer types.
__device__ __forceinline__ unsigned short f2bf(float f) {
  unsigned u = __builtin_bit_cast(unsigned, f);
  u += 0x7FFFu + ((u >> 16) & 1u);
  return (unsigned short)(u >> 16);
}
__device__ __forceinline__ unsigned packbf2(float a, float b) {
  return (unsigned)f2bf(a) | ((unsigned)f2bf(b) << 16);
}

__global__ __launch_bounds__(256, 2) void mnist_mfma(
    const float* __restrict__ x, const float* __restrict__ W1,
    const float* __restrict__ b1, const float* __restrict__ W2,
    const float* __restrict__ b2, const float* __restrict__ W3,
    const float* __restrict__ b3, float* __restrict__ out, int nimg)
{
  __shared__ __align__(16) char smem[38976];
  float* smemF = (float*)smem;
  const int tid = threadIdx.x;
  const int lane = tid & 63;
  const int waveid = tid >> 6;

  // ---- setup: stage raw W1/W2, compose W12 = W1∘W2 (bf16) + b12 ----------
  for (int i = tid; i < 784; i += 256) smemF[i] = W1[i];
  for (int i = tid; i < 1024; i += 256) smemF[784 + i] = W2[i];
  __syncthreads();

  unsigned short* w12b = (unsigned short*)(smem + WOFF);
  for (int e = tid; e < 3136; e += 256) {
    int f2 = e / 196, k = e - f2 * 196;
    int r14 = k / 14, c14 = k - r14 * 14;
    int pp = (r14 % 7) * 7 + (c14 % 7);          // within-patch pixel
    int q = (r14 / 7) * 2 + (c14 / 7);           // patch block i2*2+j2
    float s = 0.f;
#pragma unroll
    for (int f = 0; f < 16; ++f)
      s = fmaf(smemF[f * 49 + pp], smemF[784 + f2 * 64 + q * 16 + f], s);
    w12b[f2 * 232 + k] = f2bf(s);
  }
  for (int e = tid; e < 576; e += 256) {         // zero K-pad [196,232)
    int f2 = e / 36;
    w12b[f2 * 232 + 196 + (e - f2 * 36)] = 0;
  }
  if (tid < 16) {                                // b12 = b2 + b1-through-W2
    float s = b2[tid];
#pragma unroll
    for (int k = 0; k < 64; ++k)
      s = fmaf(b1[k & 15], smemF[784 + tid * 64 + k], s);
    smemF[BOFF / 4 + tid] = s;
  }
  __syncthreads();

  // ---- preload fragments into registers ----------------------------------
  bf16x8 wfrag[7];                               // W12 B-frags (28 VGPRs)
#pragma unroll
  for (int i = 0; i < 7; ++i)
    wfrag[i] = *(const bf16x8*)(smem + WOFF + (lane & 15) * XS + (lane >> 4) * 16 + i * 64);

  bf16x8 w3f[2];                                 // W3 A-frags (rows>=10 zero)
  {
    int o = lane & 15, kb = (lane >> 4) * 8;
#pragma unroll
    for (int mi = 0; mi < 2; ++mi) {
      float v[8];
#pragma unroll
      for (int j = 0; j < 8; ++j)
        v[j] = (o < 10) ? W3[o * 64 + kb + 32 * mi + j] : 0.f;
      unsigned t[4];
      t[0] = packbf2(v[0], v[1]); t[1] = packbf2(v[2], v[3]);
      t[2] = packbf2(v[4], v[5]); t[3] = packbf2(v[6], v[7]);
      w3f[mi] = __builtin_bit_cast(bf16x8, *(unsigned(*)[4])t);
    }
  }
  const float b12v = smemF[BOFF / 4 + (lane & 15)];
  float b3v[4];
#pragma unroll
  for (int r = 0; r < 4; ++r) {
    int o = (lane >> 4) * 4 + r;
    b3v[r] = (o < 10) ? b3[o] : 0.f;
  }
  // All waves have W12 in registers; y-region may now alias it.
  __syncthreads();

  // ---- per-wave zero of x-stage K-pad (bytes [392,464) of each row) ------
  char* xw = smem + waveid * 7424;
#pragma unroll
  for (int j = 0; j < 5; ++j) {
    int idx = lane + 64 * j;
    if (idx < 288) {
      int row = idx / 18, d = idx - row * 18;
      *(unsigned*)(xw + row * XS + 392 + d * 4) = 0;
    }
  }

  // ---- staging addresses: raster float4 -> quadrant-stream bf16 pairs ----
  unsigned wa0[13]; unsigned strm = 0;
#pragma unroll
  for (int it = 0; it < 13; ++it) {
    int gi = lane + 64 * it;
    int im = gi / 196, rem = gi - im * 196;      // image, float4 within image
    int rr = rem / 7, t = rem - rr * 7;          // pixel row, 4-px group
    int c2 = 2 * t;                              // first bf16-pair column
    int J = c2 / 7, cq = c2 - 7 * J;
    int row = im * 4 + (rr / 14) * 2 + J;        // M-row = im*4 + (I*2+J)
    int kp = (rr % 14) * 7 + cq;                 // pair index in quadrant
    wa0[it] = waveid * 7424 + row * XS + kp * 4;
    if (t == 3) strm |= (1u << it);              // second pair crosses J-half
  }

  const unsigned xrd = waveid * 7424 + (lane & 15) * XS + (lane >> 4) * 16;
  const unsigned ywb = YOFF + waveid * 2304 + (lane & 15) * 2;
  const unsigned yrd = YOFF + waveid * 2304 + (lane & 15) * YS + (lane >> 4) * 16;

  // ---- BLOCKED unit->wave mapping (this round's single change) -----------
  // XCD xcd = blockIdx&7 owns contiguous units [xcd*NU/8, (xcd+1)*NU/8);
  // block slot = blockIdx>>3 owns 8 contiguous units; wave owns 2 contiguous.
  // => every wave walks one contiguous 98 KB run of x, strictly sequential;
  //    every XCD's L2 serves one contiguous 1/8 of the input.
  const int NU = nimg >> 4;                      // 16-image units
  const int UPP = (int)(gridDim.x << 3);         // units per pass (all waves)
  const int ub = (int)(blockIdx.x & 7) * (NU >> 3)
               + (int)(blockIdx.x >> 3) * 8 + waveid * 2;
  const int ng4 = nimg >> 2;                     // 4-image groups total

  f32x4 cur[13];
  const f32x4* __restrict__ xq0 = (const f32x4*)x;
  auto issue4 = [&](int g4) {                    // 13 coalesced dwordx4 loads
    const f32x4* p = xq0 + (size_t)g4 * 784;
#pragma unroll
    for (int it = 0; it < 12; ++it) cur[it] = p[lane + 64 * it];
    if (lane < 16) cur[12] = p[768 + lane];
  };

  if (ub < NU) issue4(ub * 4);

  for (int u0 = ub; u0 < NU; u0 += UPP) {
#pragma unroll 1
    for (int s8 = 0; s8 < 8; ++s8) {             // 8 sequential groups = 98 KB
      const int u = u0 + (s8 >> 2);
      if (u >= NU) break;
      const int sb = s8 & 3;
      // stage cur -> LDS (compiler inserts the vmcnt wait on cur)
#pragma unroll
      for (int it = 0; it < 13; ++it) {
        if (it == 12 && lane >= 16) continue;
        f32x4 v = cur[it];
        unsigned a0 = wa0[it];
        unsigned d = ((strm >> it) & 1) ? 440u : 4u;
        *(unsigned*)(smem + a0) = packbf2(v.x, v.y);
        *(unsigned*)(smem + a0 + d) = packbf2(v.z, v.w);
      }
      // prefetch next group: sequential within the run, else next pass
      int ng = (s8 < 7) ? (u0 * 4 + s8 + 1) : ((u0 + UPP) * 4);
      if (ng < ng4) issue4(ng);
      // GEMM1: y(16 rows x 16 f2) = P(16 x 224) * W12(224 x 16)
      f32x4 acc = {0.f, 0.f, 0.f, 0.f};
#pragma unroll
      for (int i = 0; i < 7; ++i) {
        bf16x8 a = *(const bf16x8*)(smem + xrd + 64 * i);
        acc = __builtin_amdgcn_mfma_f32_16x16x32_bf16(a, wfrag[i], acc, 0, 0, 0);
      }
      // bias + ReLU + bf16 -> y LDS  (D: img=lane>>4, q=r, f2=lane&15)
      unsigned yb = ywb + (unsigned)(sb * 4 + (lane >> 4)) * YS;
#pragma unroll
      for (int r = 0; r < 4; ++r) {
        float yv = fmaxf(acc[r] + b12v, 0.f);
        *(unsigned short*)(smem + yb + r * 32) = f2bf(yv);
      }

      if (sb == 3) {                             // unit epilogue
        f32x4 z4 = {0.f, 0.f, 0.f, 0.f};
#pragma unroll
        for (int mi = 0; mi < 2; ++mi) {
          bf16x8 bfr = *(const bf16x8*)(smem + yrd + 64 * mi);
          z4 = __builtin_amdgcn_mfma_f32_16x16x32_bf16(w3f[mi], bfr, z4, 0, 0, 0);
        }
        float zv[4], mval = -3.0e38f;
#pragma unroll
        for (int r = 0; r < 4; ++r) {
          zv[r] = z4[r] + b3v[r];
          bool valid = ((lane >> 4) * 4 + r) < 10;
          mval = fmaxf(mval, valid ? zv[r] : -3.0e38f);
        }
        mval = fmaxf(mval, __shfl_xor(mval, 16, 64));
        mval = fmaxf(mval, __shfl_xor(mval, 32, 64));
        float ssum = 0.f;
#pragma unroll
        for (int r = 0; r < 4; ++r) {
          bool valid = ((lane >> 4) * 4 + r) < 10;
          ssum += valid ? __expf(zv[r] - mval) : 0.f;
        }
        ssum += __shfl_xor(ssum, 16, 64);
        ssum += __shfl_xor(ssum, 32, 64);
        const float lse = mval + __logf(ssum);
        float* op = out + (size_t)(u * 16 + (lane & 15)) * 10;
#pragma unroll
        for (int r = 0; r < 4; ++r) {
          int o = (lane >> 4) * 4 + r;
          if (o < 10) op[o] = zv[r] - lse;
        }
      }
    }
  }
}

extern "C" void kernel_launch(void* const* d_in, const int* in_sizes, int n_in,
                              void* d_out, int out_size, void* d_ws, size_t ws_size,
                              hipStream_t stream) {
  const float* x  = (const float*)d_in[0];
  const float* W1 = (const float*)d_in[1];
  const float* b1 = (const float*)d_in[2];
  const float* W2 = (const float*)d_in[3];
  const float* b2 = (const float*)d_in[4];
  const float* W3 = (const float*)d_in[5];
  const float* b3 = (const float*)d_in[6];
  float* out = (float*)d_out;

  const int nimg = in_sizes[0] / 784;  // 131072
  // 1024 blocks x 4 waves, blocked-contiguous partition: 8192 units exactly
  // cover nimg; every wave reads one contiguous 98 KB run.
  mnist_mfma<<<1024, 256, 0, stream>>>(x, W1, b1, W2, b2, W3, b3, out, nimg);
}

// Round 10
// 75.125 us; speedup vs baseline: 1.2315x; 1.1651x over previous
//
#include <hip/hip_runtime.h>

typedef float f32x4 __attribute__((ext_vector_type(4)));
typedef short bf16x8 __attribute__((ext_vector_type(8)));

// LDS map (bytes):
//   [0, 29696)      per-wave x-stage: 4 waves x 16 rows x 464B (224 bf16 + pad)
//                   (setup reuses [0,7232) to stage raw W1/W2 for compose)
//   [29696, 37120)  W12 bf16 (setup only; preloaded to regs, then DEAD)
//   [29696, 38912)  per-wave y (ALIASES W12 after preload): 4 x 16 x 144B
//   [38912, 38976)  b12 (16 f32)
// Total 38976 B -> 4 blocks/CU (155.9 KB of 160 KB).
#define XS 464
#define WOFF 29696
#define YOFF 29696
#define YS 144
#define BOFF 38912

// RNE float->bf16 on plain integer types.
__device__ __forceinline__ unsigned short f2bf(float f) {
  unsigned u = __builtin_bit_cast(unsigned, f);
  u += 0x7FFFu + ((u >> 16) & 1u);
  return (unsigned short)(u >> 16);
}
__device__ __forceinline__ unsigned packbf2(float a, float b) {
  return (unsigned)f2bf(a) | ((unsigned)f2bf(b) << 16);
}

__global__ __launch_bounds__(256, 2) void mnist_mfma(
    const float* __restrict__ x, const float* __restrict__ W1,
    const float* __restrict__ b1, const float* __restrict__ W2,
    const float* __restrict__ b2, const float* __restrict__ W3,
    const float* __restrict__ b3, float* __restrict__ out, int nimg)
{
  __shared__ __align__(16) char smem[38976];
  float* smemF = (float*)smem;
  const int tid = threadIdx.x;
  const int lane = tid & 63;
  const int waveid = tid >> 6;

  // ---- setup: stage raw W1/W2, compose W12 = W1∘W2 (bf16) + b12 ----------
  for (int i = tid; i < 784; i += 256) smemF[i] = W1[i];
  for (int i = tid; i < 1024; i += 256) smemF[784 + i] = W2[i];
  __syncthreads();

  unsigned short* w12b = (unsigned short*)(smem + WOFF);
  for (int e = tid; e < 3136; e += 256) {
    int f2 = e / 196, k = e - f2 * 196;
    int r14 = k / 14, c14 = k - r14 * 14;
    int pp = (r14 % 7) * 7 + (c14 % 7);          // within-patch pixel
    int q = (r14 / 7) * 2 + (c14 / 7);           // patch block i2*2+j2
    float s = 0.f;
#pragma unroll
    for (int f = 0; f < 16; ++f)
      s = fmaf(smemF[f * 49 + pp], smemF[784 + f2 * 64 + q * 16 + f], s);
    w12b[f2 * 232 + k] = f2bf(s);
  }
  for (int e = tid; e < 576; e += 256) {         // zero K-pad [196,232)
    int f2 = e / 36;
    w12b[f2 * 232 + 196 + (e - f2 * 36)] = 0;
  }
  if (tid < 16) {                                // b12 = b2 + b1-through-W2
    float s = b2[tid];
#pragma unroll
    for (int k = 0; k < 64; ++k)
      s = fmaf(b1[k & 15], smemF[784 + tid * 64 + k], s);
    smemF[BOFF / 4 + tid] = s;
  }
  __syncthreads();

  // ---- preload fragments into registers ----------------------------------
  bf16x8 wfrag[7];                               // W12 B-frags (28 VGPRs)
#pragma unroll
  for (int i = 0; i < 7; ++i)
    wfrag[i] = *(const bf16x8*)(smem + WOFF + (lane & 15) * XS + (lane >> 4) * 16 + i * 64);

  bf16x8 w3f[2];                                 // W3 A-frags (rows>=10 zero)
  {
    int o = lane & 15, kb = (lane >> 4) * 8;
#pragma unroll
    for (int mi = 0; mi < 2; ++mi) {
      float v[8];
#pragma unroll
      for (int j = 0; j < 8; ++j)
        v[j] = (o < 10) ? W3[o * 64 + kb + 32 * mi + j] : 0.f;
      unsigned t[4];
      t[0] = packbf2(v[0], v[1]); t[1] = packbf2(v[2], v[3]);
      t[2] = packbf2(v[4], v[5]); t[3] = packbf2(v[6], v[7]);
      w3f[mi] = __builtin_bit_cast(bf16x8, *(unsigned(*)[4])t);
    }
  }
  const float b12v = smemF[BOFF / 4 + (lane & 15)];
  float b3v[4];
#pragma unroll
  for (int r = 0; r < 4; ++r) {
    int o = (lane >> 4) * 4 + r;
    b3v[r] = (o < 10) ? b3[o] : 0.f;
  }
  // All waves have W12 in registers; y-region may now alias it.
  __syncthreads();

  // ---- per-wave zero of x-stage K-pad (bytes [392,464) of each row) ------
  char* xw = smem + waveid * 7424;
#pragma unroll
  for (int j = 0; j < 5; ++j) {
    int idx = lane + 64 * j;
    if (idx < 288) {
      int row = idx / 18, d = idx - row * 18;
      *(unsigned*)(xw + row * XS + 392 + d * 4) = 0;
    }
  }

  // ---- staging addresses: raster float4 -> quadrant-stream bf16 pairs ----
  unsigned wa0[13]; unsigned strm = 0;
#pragma unroll
  for (int it = 0; it < 13; ++it) {
    int gi = lane + 64 * it;
    int im = gi / 196, rem = gi - im * 196;      // image, float4 within image
    int rr = rem / 7, t = rem - rr * 7;          // pixel row, 4-px group
    int c2 = 2 * t;                              // first bf16-pair column
    int J = c2 / 7, cq = c2 - 7 * J;
    int row = im * 4 + (rr / 14) * 2 + J;        // M-row = im*4 + (I*2+J)
    int kp = (rr % 14) * 7 + cq;                 // pair index in quadrant
    wa0[it] = waveid * 7424 + row * XS + kp * 4;
    if (t == 3) strm |= (1u << it);              // second pair crosses J-half
  }

  const unsigned xrd = waveid * 7424 + (lane & 15) * XS + (lane >> 4) * 16;
  const unsigned ywb = YOFF + waveid * 2304 + (lane & 15) * 2;
  const unsigned yrd = YOFF + waveid * 2304 + (lane & 15) * YS + (lane >> 4) * 16;

  const int NU = nimg >> 4;                      // 16-image units
  const int WST = (int)(gridDim.x << 2);         // total waves
  const int w0 = (int)(blockIdx.x << 2) + waveid;
  const int ng4 = nimg >> 2;                     // 4-image groups

  f32x4 cur[13];
  const f32x4* __restrict__ xq0 = (const f32x4*)x;
  auto issue4 = [&](int g4) {                    // 13 coalesced NT dwordx4 loads
    const f32x4* p = xq0 + (size_t)g4 * 784;
#pragma unroll
    for (int it = 0; it < 12; ++it)
      cur[it] = __builtin_nontemporal_load(p + lane + 64 * it);
    if (lane < 16) cur[12] = __builtin_nontemporal_load(p + 768 + lane);
  };

  if (w0 < NU) issue4(w0 * 4);

  for (int u = w0; u < NU; u += WST) {
#pragma unroll 1
    for (int sb = 0; sb < 4; ++sb) {
      // stage cur -> LDS (compiler inserts the vmcnt wait on cur)
#pragma unroll
      for (int it = 0; it < 13; ++it) {
        if (it == 12 && lane >= 16) continue;
        f32x4 v = cur[it];
        unsigned a0 = wa0[it];
        unsigned d = ((strm >> it) & 1) ? 440u : 4u;
        *(unsigned*)(smem + a0) = packbf2(v.x, v.y);
        *(unsigned*)(smem + a0 + d) = packbf2(v.z, v.w);
      }
      // prefetch next 4-image group (1 sub-batch deep)
      int ng = (sb < 3) ? (u * 4 + sb + 1) : ((u + WST) * 4);
      if (ng < ng4) issue4(ng);
      // GEMM1: y(16 rows x 16 f2) = P(16 x 224) * W12(224 x 16)
      f32x4 acc = {0.f, 0.f, 0.f, 0.f};
#pragma unroll
      for (int i = 0; i < 7; ++i) {
        bf16x8 a = *(const bf16x8*)(smem + xrd + 64 * i);
        acc = __builtin_amdgcn_mfma_f32_16x16x32_bf16(a, wfrag[i], acc, 0, 0, 0);
      }
      // bias + ReLU + bf16 -> y LDS  (D: img=lane>>4, q=r, f2=lane&15)
      unsigned yb = ywb + (unsigned)(sb * 4 + (lane >> 4)) * YS;
#pragma unroll
      for (int r = 0; r < 4; ++r) {
        float yv = fmaxf(acc[r] + b12v, 0.f);
        *(unsigned short*)(smem + yb + r * 32) = f2bf(yv);
      }
    }
    // GEMM2: z^T(16 o x 16 img) = W3(16x64) * y^T(64x16) over the unit
    f32x4 z4 = {0.f, 0.f, 0.f, 0.f};
#pragma unroll
    for (int mi = 0; mi < 2; ++mi) {
      bf16x8 bfr = *(const bf16x8*)(smem + yrd + 64 * mi);
      z4 = __builtin_amdgcn_mfma_f32_16x16x32_bf16(w3f[mi], bfr, z4, 0, 0, 0);
    }
    // log_softmax over o = (lane>>4)*4 + r (10 valid), img = lane&15
    float zv[4], mval = -3.0e38f;
#pragma unroll
    for (int r = 0; r < 4; ++r) {
      zv[r] = z4[r] + b3v[r];
      bool valid = ((lane >> 4) * 4 + r) < 10;
      mval = fmaxf(mval, valid ? zv[r] : -3.0e38f);
    }
    mval = fmaxf(mval, __shfl_xor(mval, 16, 64));
    mval = fmaxf(mval, __shfl_xor(mval, 32, 64));
    float ssum = 0.f;
#pragma unroll
    for (int r = 0; r < 4; ++r) {
      bool valid = ((lane >> 4) * 4 + r) < 10;
      ssum += valid ? __expf(zv[r] - mval) : 0.f;
    }
    ssum += __shfl_xor(ssum, 16, 64);
    ssum += __shfl_xor(ssum, 32, 64);
    const float lse = mval + __logf(ssum);
    float* op = out + (size_t)(u * 16 + (lane & 15)) * 10;
#pragma unroll
    for (int r = 0; r < 4; ++r) {
      int o = (lane >> 4) * 4 + r;
      if (o < 10) op[o] = zv[r] - lse;
    }
  }
}

extern "C" void kernel_launch(void* const* d_in, const int* in_sizes, int n_in,
                              void* d_out, int out_size, void* d_ws, size_t ws_size,
                              hipStream_t stream) {
  const float* x  = (const float*)d_in[0];
  const float* W1 = (const float*)d_in[1];
  const float* b1 = (const float*)d_in[2];
  const float* W2 = (const float*)d_in[3];
  const float* b2 = (const float*)d_in[4];
  const float* W3 = (const float*)d_in[5];
  const float* b3 = (const float*)d_in[6];
  float* out = (float*)d_out;

  const int nimg = in_sizes[0] / 784;  // 131072
  // 1024 blocks = 4096 waves -> exactly 2 units/wave; 4 blocks/CU at 39 KB LDS.
  mnist_mfma<<<1024, 256, 0, stream>>>(x, W1, b1, W2, b2, W3, b3, out, nimg);
}